// Round 5
// baseline (163.250 us; speedup 1.0000x reference)
//
#include <hip/hip_runtime.h>
#include <math.h>

#define BB 2
#define SS 2048
#define EE 1024
#define HH 16
#define DD 64

typedef unsigned short u16;
typedef __attribute__((ext_vector_type(8))) short short8;
typedef __attribute__((ext_vector_type(4))) float f32x4;

__device__ __forceinline__ u16 f2bf(float x) {
    union { float f; unsigned u; } v; v.f = x;
    return (u16)((v.u + 0x7fffu + ((v.u >> 16) & 1u)) >> 16);
}

__device__ __forceinline__ float exp2_fast(float x) {
    float r;
    asm("v_exp_f32 %0, %1" : "=v"(r) : "v"(x));
    return r;
}

#define GLL16(gp, lp) \
    __builtin_amdgcn_global_load_lds( \
        (const __attribute__((address_space(1))) void*)(gp), \
        (__attribute__((address_space(3))) void*)(lp), 16, 0, 0)

#define WAIT_VM4 asm volatile("s_waitcnt vmcnt(4)" ::: "memory")
#define WAIT_VM3 asm volatile("s_waitcnt vmcnt(3)" ::: "memory")
#define WAIT_VM0 asm volatile("s_waitcnt vmcnt(0)" ::: "memory")
#define WAIT_LG0 asm volatile("s_waitcnt lgkmcnt(0)" ::: "memory")
#define SBAR __builtin_amdgcn_s_barrier()
#define SCHEDB __builtin_amdgcn_sched_barrier(0)

// QSCALE = (1/sqrt(64)) * log2(e): softmax computed in base-2
#define QSCALE 0.18033688f

// ---------------------------------------------------------------------------
// fp32 -> bf16 conversion: z = 0..2 activations (4M elems), 3..6 weights (1M)
// ---------------------------------------------------------------------------
__global__ __launch_bounds__(256)
void cvt_bf16(const float* __restrict__ s0, const float* __restrict__ s1,
              const float* __restrict__ s2, const float* __restrict__ s3,
              const float* __restrict__ s4, const float* __restrict__ s5,
              const float* __restrict__ s6,
              u16* __restrict__ d0, u16* __restrict__ d1, u16* __restrict__ d2,
              u16* __restrict__ d3, u16* __restrict__ d4, u16* __restrict__ d5,
              u16* __restrict__ d6)
{
    const int z = blockIdx.y;
    const float* s; u16* d; int n;
    switch (z) {
        case 0: s = s0; d = d0; n = 4194304; break;
        case 1: s = s1; d = d1; n = 4194304; break;
        case 2: s = s2; d = d2; n = 4194304; break;
        case 3: s = s3; d = d3; n = 1048576; break;
        case 4: s = s4; d = d4; n = 1048576; break;
        case 5: s = s5; d = d5; n = 1048576; break;
        default: s = s6; d = d6; n = 1048576; break;
    }
    const int i = (blockIdx.x * 256 + threadIdx.x) * 8;
    if (i >= n) return;
    float4 a = *(const float4*)(s + i);
    float4 b = *(const float4*)(s + i + 4);
    short8 r;
    r[0] = (short)f2bf(a.x); r[1] = (short)f2bf(a.y);
    r[2] = (short)f2bf(a.z); r[3] = (short)f2bf(a.w);
    r[4] = (short)f2bf(b.x); r[5] = (short)f2bf(b.y);
    r[6] = (short)f2bf(b.z); r[7] = (short)f2bf(b.w);
    *(short8*)(d + i) = r;
}

// ---------------------------------------------------------------------------
// Fused QKV GEMM, counted-vmcnt depth-2 pipeline (T4).
// 1D grid 768 XCD-swizzled; 128x128 tile, BK=32, 4 waves.
// Per iter: ds_read tile k -> regs, lgkm0+bar, STAGE(k+2) into freed buffer,
// MFMA (overlaps loads), vmcnt(4)+bar (tile k+1 landed: issued 1 iter ago).
// z=0: Q scatter [b,h][s][d] scaled QSCALE; z=1: K scatter; z=2: V transposed.
// ---------------------------------------------------------------------------
__global__ __launch_bounds__(256)
void gemm_qkv(const u16* __restrict__ Xq, const u16* __restrict__ Xk,
              const u16* __restrict__ Xv,
              const u16* __restrict__ Wqb, const u16* __restrict__ Wkb,
              const u16* __restrict__ Wvb,
              const float* __restrict__ bq, const float* __restrict__ bk,
              const float* __restrict__ bv,
              u16* __restrict__ Qh, u16* __restrict__ Kh, u16* __restrict__ Vth)
{
    __shared__ __align__(16) u16 As[2][4][128][8];   // 16 KB
    __shared__ __align__(16) u16 Bs[2][4][128][8];   // 16 KB

    const int bid = blockIdx.x;
    const int swz = (bid & 7) * 96 + (bid >> 3);     // bijective, 768 = 8*96
    const int z   = swz >> 8;
    const int rem = swz & 255;
    const int m0  = (rem >> 3) * 128;
    const int n0  = (rem & 7) * 128;

    const u16* X = (z == 0) ? Xq : (z == 1) ? Xk : Xv;
    const u16* W = (z == 0) ? Wqb : (z == 1) ? Wkb : Wvb;
    const float* bias = (z == 0) ? bq : (z == 1) ? bk : bv;
    u16* out = (z == 0) ? Qh : (z == 1) ? Kh : Vth;

    const int t = threadIdx.x;
    const int w = t >> 6, l = t & 63;
    const int ln = l & 15, hi = l >> 4;
    const int wr = w >> 1, wc = w & 1;

    f32x4 acc[4][4];
    #pragma unroll
    for (int i = 0; i < 4; i++)
        #pragma unroll
        for (int j = 0; j < 4; j++)
            acc[i][j] = (f32x4){0.f, 0.f, 0.f, 0.f};

#define QSTAGE(buf, k0_)                                                     \
    {                                                                        \
        _Pragma("unroll")                                                    \
        for (int i_ = 0; i_ < 4; i_++) {                                     \
            const int id_ = w + i_ * 4;                                      \
            const int tensor_ = id_ >> 3, kg_ = (id_ >> 1) & 3, mh_ = id_ & 1;\
            const u16* g_ = tensor_ ? W : X;                                 \
            const int row_ = (tensor_ ? n0 : m0) + mh_ * 64 + l;             \
            const u16* gp_ = g_ + (size_t)row_ * 1024 + (k0_) + kg_ * 8;     \
            u16* lp_ = tensor_ ? &Bs[buf][kg_][mh_ * 64][0]                  \
                               : &As[buf][kg_][mh_ * 64][0];                 \
            GLL16(gp_, lp_);                                                 \
        }                                                                    \
    }

#define QCOMPUTE(buf)                                                        \
    {                                                                        \
        _Pragma("unroll")                                                    \
        for (int mi = 0; mi < 4; mi++)                                       \
            af[mi] = *(const short8*)&As[buf][hi][wr * 64 + mi * 16 + ln][0];\
        _Pragma("unroll")                                                    \
        for (int nj = 0; nj < 4; nj++)                                       \
            bfr[nj] = *(const short8*)&Bs[buf][hi][wc * 64 + nj * 16 + ln][0];\
    }

#define QMFMA                                                                \
    {                                                                        \
        _Pragma("unroll")                                                    \
        for (int mi = 0; mi < 4; mi++)                                       \
            _Pragma("unroll")                                                \
            for (int nj = 0; nj < 4; nj++)                                   \
                acc[mi][nj] = __builtin_amdgcn_mfma_f32_16x16x32_bf16(       \
                    af[mi], bfr[nj], acc[mi][nj], 0, 0, 0);                  \
    }

    QSTAGE(0, 0);
    QSTAGE(1, 32);
    WAIT_VM4;            // tile 0 landed (own 4 oldest loads)
    SBAR;                // -> all waves' tile-0 loads landed
    short8 af[4], bfr[4];
    #pragma unroll 2
    for (int kt = 0; kt < 30; kt++) {
        const int cur = kt & 1;
        QCOMPUTE(cur);   // ds_read tile kt -> regs
        WAIT_LG0;        // reads complete before buffer overwrite
        SCHEDB;
        SBAR;
        QSTAGE(cur, kt * 32 + 64);   // stage tile kt+2 into freed buffer
        QMFMA;           // register-only; overlaps in-flight loads
        WAIT_VM4;        // tile kt+1 loads landed (issued one iter ago)
        SBAR;
    }
    // tails: tile 30 (buf 0), tile 31 (buf 1)
    QCOMPUTE(0);
    QMFMA;
    WAIT_VM0;            // own tile-31 loads landed
    SBAR;                // all waves' tile-31 loads landed
    QCOMPUTE(1);
    QMFMA;
#undef QSTAGE
#undef QCOMPUTE
#undef QMFMA

    #pragma unroll
    for (int mi = 0; mi < 4; mi++) {
        #pragma unroll
        for (int nj = 0; nj < 4; nj++) {
            const int nb = n0 + wc * 64 + nj * 16 + ln;
            const float bv2 = bias[nb];
            #pragma unroll
            for (int r = 0; r < 4; r++) {
                const int m = m0 + wr * 64 + mi * 16 + hi * 4 + r;
                float v = acc[mi][nj][r] + bv2;
                if (z == 0) v *= QSCALE;
                const int b = m >> 11, s = m & 2047;
                const int h = nb >> 6, d = nb & 63;
                if (z == 2)
                    out[(((size_t)(b * HH + h) * 64 + d) << 11) + s] = f2bf(v);
                else
                    out[((((size_t)(b * HH + h)) << 11) + s) * 64 + d] = f2bf(v);
            }
        }
    }
}

// ---------------------------------------------------------------------------
// Output projection GEMM, counted-vmcnt depth-2 pipeline. 64x128 tile,
// 1D grid 512 XCD-swizzled, fp32 out + bias. 3 loads/wave/stage -> vmcnt(3).
// ---------------------------------------------------------------------------
__global__ __launch_bounds__(256)
void gemm_out(const u16* __restrict__ Xb, const u16* __restrict__ Wb,
              const float* __restrict__ bias, float* __restrict__ outp)
{
    __shared__ __align__(16) u16 As[2][4][64][8];    // 8 KB
    __shared__ __align__(16) u16 Bs[2][4][128][8];   // 16 KB

    const int bid = blockIdx.x;
    const int swz = (bid & 7) * 64 + (bid >> 3);     // bijective, 512 = 8*64
    const int m0  = (swz >> 3) * 64;
    const int n0  = (swz & 7) * 128;

    const int t = threadIdx.x;
    const int w = t >> 6, l = t & 63;
    const int ln = l & 15, hi = l >> 4;
    const int wr = w >> 1, wc = w & 1;

    f32x4 acc[2][4];
    #pragma unroll
    for (int i = 0; i < 2; i++)
        #pragma unroll
        for (int j = 0; j < 4; j++)
            acc[i][j] = (f32x4){0.f, 0.f, 0.f, 0.f};

#define OSTAGE(buf, k0_)                                                     \
    {                                                                        \
        _Pragma("unroll")                                                    \
        for (int i_ = 0; i_ < 3; i_++) {                                     \
            const int id_ = w + i_ * 4;                                      \
            if (id_ < 4) {                                                   \
                const u16* gp_ = Xb + (size_t)(m0 + l) * 1024 + (k0_) + id_ * 8;\
                GLL16(gp_, &As[buf][id_][0][0]);                             \
            } else {                                                         \
                const int idb_ = id_ - 4, kg_ = idb_ & 3, half_ = idb_ >> 2; \
                const u16* gp_ = Wb + (size_t)(n0 + half_ * 64 + l) * 1024   \
                                 + (k0_) + kg_ * 8;                          \
                GLL16(gp_, &Bs[buf][kg_][half_ * 64][0]);                    \
            }                                                                \
        }                                                                    \
    }

#define OCOMPUTE(buf)                                                        \
    {                                                                        \
        _Pragma("unroll")                                                    \
        for (int mi = 0; mi < 2; mi++)                                       \
            af[mi] = *(const short8*)&As[buf][hi][wr * 32 + mi * 16 + ln][0];\
        _Pragma("unroll")                                                    \
        for (int nj = 0; nj < 4; nj++)                                       \
            bfr[nj] = *(const short8*)&Bs[buf][hi][wc * 64 + nj * 16 + ln][0];\
    }

#define OMFMA                                                                \
    {                                                                        \
        _Pragma("unroll")                                                    \
        for (int mi = 0; mi < 2; mi++)                                       \
            _Pragma("unroll")                                                \
            for (int nj = 0; nj < 4; nj++)                                   \
                acc[mi][nj] = __builtin_amdgcn_mfma_f32_16x16x32_bf16(       \
                    af[mi], bfr[nj], acc[mi][nj], 0, 0, 0);                  \
    }

    OSTAGE(0, 0);
    OSTAGE(1, 32);
    WAIT_VM3;
    SBAR;
    short8 af[2], bfr[4];
    #pragma unroll 2
    for (int kt = 0; kt < 30; kt++) {
        const int cur = kt & 1;
        OCOMPUTE(cur);
        WAIT_LG0;
        SCHEDB;
        SBAR;
        OSTAGE(cur, kt * 32 + 64);
        OMFMA;
        WAIT_VM3;
        SBAR;
    }
    OCOMPUTE(0);
    OMFMA;
    WAIT_VM0;
    SBAR;
    OCOMPUTE(1);
    OMFMA;
#undef OSTAGE
#undef OCOMPUTE
#undef OMFMA

    #pragma unroll
    for (int mi = 0; mi < 2; mi++) {
        #pragma unroll
        for (int nj = 0; nj < 4; nj++) {
            const int nb = n0 + wc * 64 + nj * 16 + ln;
            const float bv2 = bias[nb];
            #pragma unroll
            for (int r = 0; r < 4; r++) {
                const int m = m0 + wr * 32 + mi * 16 + hi * 4 + r;
                outp[(size_t)m * 1024 + nb] = acc[mi][nj][r] + bv2;
            }
        }
    }
}

// ---------------------------------------------------------------------------
// Flash attention, bf16 MFMA (unchanged: compute phase covers prefetch).
// ---------------------------------------------------------------------------
__global__ __launch_bounds__(256)
void attn_mfma(const u16* __restrict__ Qh, const u16* __restrict__ Kh,
               const u16* __restrict__ Vt, u16* __restrict__ Cc)
{
    __shared__ __align__(16) u16 Ks[2][2][4][64][8];  // 16KB
    __shared__ __align__(16) u16 Vs[2][2][4][64][8];  // 16KB
    __shared__ __align__(16) u16 Ps[4][16][64];       // 8KB
    const int bh = blockIdx.x;
    const int y  = 31 - blockIdx.y;        // longest blocks dispatch first
    const int q0 = y * 64;
    const int t = threadIdx.x, w = t >> 6, l = t & 63;
    const int ln = l & 15, hi = l >> 4;
    const size_t base = (size_t)bh * SS * DD;
    const int qg = q0 + w * 16 + ln;

    short8 qf0, qf1;
    {
        const u16* qp = Qh + base + (size_t)qg * 64 + hi * 8;
        qf0 = *(const short8*)qp;
        qf1 = *(const short8*)(qp + 32);
    }
    f32x4 o[4];
    #pragma unroll
    for (int dj = 0; dj < 4; dj++) o[dj] = (f32x4){0.f, 0.f, 0.f, 0.f};
    float mrun = -INFINITY, lrun = 0.f;

#define STAGE(buf, key0_)                                                        \
    {                                                                            \
        _Pragma("unroll")                                                        \
        for (int i_ = 0; i_ < 4; i_++) {                                         \
            const int id_ = w + i_ * 4;                                          \
            if (id_ < 8) {                                                       \
                const int dc_ = id_ >> 2, kg_ = id_ & 3;                         \
                const u16* gp_ = Kh + base + (size_t)((key0_) + l) * 64          \
                                 + dc_ * 32 + kg_ * 8;                           \
                GLL16(gp_, &Ks[buf][dc_][kg_][0][0]);                            \
            } else {                                                             \
                const int kc_ = (id_ >> 2) & 1, kg_ = id_ & 3;                   \
                const u16* gp_ = Vt + base + (size_t)l * SS + (key0_)            \
                                 + kc_ * 32 + kg_ * 8;                           \
                GLL16(gp_, &Vs[buf][kc_][kg_][0][0]);                            \
            }                                                                    \
        }                                                                        \
    }

    STAGE(0, 0);
    __syncthreads();
    int cur = 0;
    const int nkt = y + 1;
    for (int kt = 0; kt < nkt; kt++) {
        const int key0 = kt * 64;
        if (kt + 1 < nkt) STAGE(cur ^ 1, key0 + 64);

        f32x4 st[4];
        #pragma unroll
        for (int kt4 = 0; kt4 < 4; kt4++) {
            short8 ka = *(const short8*)&Ks[cur][0][hi][kt4 * 16 + ln][0];
            short8 kb = *(const short8*)&Ks[cur][1][hi][kt4 * 16 + ln][0];
            f32x4 zz = (f32x4){0.f, 0.f, 0.f, 0.f};
            zz = __builtin_amdgcn_mfma_f32_16x16x32_bf16(ka, qf0, zz, 0, 0, 0);
            zz = __builtin_amdgcn_mfma_f32_16x16x32_bf16(kb, qf1, zz, 0, 0, 0);
            st[kt4] = zz;
        }
        if (kt == y) {
            #pragma unroll
            for (int kt4 = 0; kt4 < 4; kt4++)
                #pragma unroll
                for (int r = 0; r < 4; r++)
                    if (key0 + kt4 * 16 + hi * 4 + r > qg)
                        st[kt4][r] = -INFINITY;
        }

        float tmax = -INFINITY;
        #pragma unroll
        for (int kt4 = 0; kt4 < 4; kt4++)
            #pragma unroll
            for (int r = 0; r < 4; r++)
                tmax = fmaxf(tmax, st[kt4][r]);
        tmax = fmaxf(tmax, __shfl_xor(tmax, 16));
        tmax = fmaxf(tmax, __shfl_xor(tmax, 32));
        if (__ballot(tmax > mrun + 8.f)) {      // deferred-max rescale (T13)
            const float mnew = fmaxf(mrun, tmax);
            const float alpha = exp2_fast(mrun - mnew);
            lrun *= alpha;
            mrun = mnew;
            #pragma unroll
            for (int r = 0; r < 4; r++) {
                const float ar = __shfl(alpha, hi * 4 + r);
                #pragma unroll
                for (int dj = 0; dj < 4; dj++) o[dj][r] *= ar;
            }
        }
        float p[4][4];
        float lsum = 0.f;
        #pragma unroll
        for (int kt4 = 0; kt4 < 4; kt4++)
            #pragma unroll
            for (int r = 0; r < 4; r++) {
                p[kt4][r] = exp2_fast(st[kt4][r] - mrun);
                lsum += p[kt4][r];
            }
        lsum += __shfl_xor(lsum, 16);
        lsum += __shfl_xor(lsum, 32);
        lrun += lsum;

        char* prow = ((char*)Ps) + (w * 16 + ln) * 128 + (hi & 1) * 8;
        #pragma unroll
        for (int kt4 = 0; kt4 < 4; kt4++) {
            unsigned dw0, dw1;
            asm("v_cvt_pk_bf16_f32 %0, %1, %2" : "=v"(dw0)
                : "v"(p[kt4][0]), "v"(p[kt4][1]));
            asm("v_cvt_pk_bf16_f32 %0, %1, %2" : "=v"(dw1)
                : "v"(p[kt4][2]), "v"(p[kt4][3]));
            const int g = (2 * kt4 + (hi >> 1)) ^ (ln & 7);
            *(uint2*)(prow + g * 16) = make_uint2(dw0, dw1);
        }

        #pragma unroll
        for (int kc = 0; kc < 2; kc++) {
            const int gr = (kc * 4 + hi) ^ (ln & 7);
            short8 pa = *(const short8*)(((char*)Ps) + (w * 16 + ln) * 128 + gr * 16);
            #pragma unroll
            for (int dj = 0; dj < 4; dj++) {
                short8 vb = *(const short8*)&Vs[cur][kc][hi][dj * 16 + ln][0];
                o[dj] = __builtin_amdgcn_mfma_f32_16x16x32_bf16(pa, vb, o[dj], 0, 0, 0);
            }
        }
        __syncthreads();
        cur ^= 1;
    }
#undef STAGE

    const float inv = 1.f / lrun;
    #pragma unroll
    for (int r = 0; r < 4; r++) {
        const float ir = __shfl(inv, hi * 4 + r);
        const int s = q0 + w * 16 + hi * 4 + r;
        const size_t ob = ((size_t)(bh >> 4) * SS + s) * EE + (bh & 15) * 64;
        #pragma unroll
        for (int dj = 0; dj < 4; dj++)
            Cc[ob + dj * 16 + ln] = f2bf(o[dj][r] * ir);
    }
}

extern "C" void kernel_launch(void* const* d_in, const int* in_sizes, int n_in,
                              void* d_out, int out_size, void* d_ws, size_t ws_size,
                              hipStream_t stream)
{
    (void)in_sizes; (void)n_in; (void)out_size; (void)ws_size;
    const float* query = (const float*)d_in[0];
    const float* key   = (const float*)d_in[1];
    const float* value = (const float*)d_in[2];
    // d_in[3] = mask: exactly causal tril, implemented analytically
    const float* Wq = (const float*)d_in[4];
    const float* bq = (const float*)d_in[5];
    const float* Wk = (const float*)d_in[6];
    const float* bk = (const float*)d_in[7];
    const float* Wv = (const float*)d_in[8];
    const float* bv = (const float*)d_in[9];
    const float* Wo = (const float*)d_in[10];
    const float* bo = (const float*)d_in[11];
    float* out = (float*)d_out;

    char* ws = (char*)d_ws;
    u16* Xq = (u16*)(ws);                         // 8 MiB
    u16* Xk = (u16*)(ws + 8388608);               // 8 MiB
    u16* Xv = (u16*)(ws + 16777216);              // 8 MiB
    u16* Wqb = (u16*)(ws + 25165824);             // 2 MiB
    u16* Wkb = (u16*)(ws + 27262976);             // 2 MiB
    u16* Wvb = (u16*)(ws + 29360128);             // 2 MiB
    u16* Wob = (u16*)(ws + 31457280);             // 2 MiB
    u16* Qh  = (u16*)(ws + 33554432);             // 8 MiB [b,h][s][d]
    u16* Kh  = (u16*)(ws + 41943040);             // 8 MiB [b,h][s][d]
    u16* Vth = (u16*)(ws + 50331648);             // 8 MiB [b,h][d][s]
    u16* Cc  = (u16*)(ws + 58720256);             // 8 MiB [b][s][e]

    cvt_bf16<<<dim3(2048, 7), 256, 0, stream>>>(
        query, key, value, Wq, Wk, Wv, Wo,
        Xq, Xk, Xv, Wqb, Wkb, Wvb, Wob);

    gemm_qkv<<<768, 256, 0, stream>>>(
        Xq, Xk, Xv, Wqb, Wkb, Wvb, bq, bk, bv, Qh, Kh, Vth);
    attn_mfma<<<dim3(32, 32), 256, 0, stream>>>(Qh, Kh, Vth, Cc);
    gemm_out<<<512, 256, 0, stream>>>(Cc, Wob, bo, out);
}

// Round 6
// 162.540 us; speedup vs baseline: 1.0044x; 1.0044x over previous
//
#include <hip/hip_runtime.h>
#include <math.h>

#define BB 2
#define SS 2048
#define EE 1024
#define HH 16
#define DD 64

typedef unsigned short u16;
typedef __attribute__((ext_vector_type(8))) short short8;
typedef __attribute__((ext_vector_type(4))) float f32x4;

__device__ __forceinline__ u16 f2bf(float x) {
    union { float f; unsigned u; } v; v.f = x;
    return (u16)((v.u + 0x7fffu + ((v.u >> 16) & 1u)) >> 16);
}

__device__ __forceinline__ float exp2_fast(float x) {
    float r;
    asm("v_exp_f32 %0, %1" : "=v"(r) : "v"(x));
    return r;
}

#define GLL16(gp, lp) \
    __builtin_amdgcn_global_load_lds( \
        (const __attribute__((address_space(1))) void*)(gp), \
        (__attribute__((address_space(3))) void*)(lp), 16, 0, 0)

#define BARRIER do { asm volatile("" ::: "memory"); \
                     __builtin_amdgcn_s_barrier();  \
                     asm volatile("" ::: "memory"); } while (0)
#define VMW8 asm volatile("s_waitcnt vmcnt(8)" ::: "memory")
#define VMW4 asm volatile("s_waitcnt vmcnt(4)" ::: "memory")
#define VMW0 asm volatile("s_waitcnt vmcnt(0)" ::: "memory")

// QSCALE = (1/sqrt(64)) * log2(e): softmax computed in base-2
#define QSCALE 0.18033688f

// ---------------------------------------------------------------------------
// fp32 -> bf16 conversion
// ---------------------------------------------------------------------------
__global__ __launch_bounds__(256)
void cvt_bf16(const float* __restrict__ s0, const float* __restrict__ s1,
              const float* __restrict__ s2, const float* __restrict__ s3,
              const float* __restrict__ s4, const float* __restrict__ s5,
              const float* __restrict__ s6,
              u16* __restrict__ d0, u16* __restrict__ d1, u16* __restrict__ d2,
              u16* __restrict__ d3, u16* __restrict__ d4, u16* __restrict__ d5,
              u16* __restrict__ d6)
{
    const int z = blockIdx.y;
    const float* s; u16* d; int n;
    switch (z) {
        case 0: s = s0; d = d0; n = 4194304; break;
        case 1: s = s1; d = d1; n = 4194304; break;
        case 2: s = s2; d = d2; n = 4194304; break;
        case 3: s = s3; d = d3; n = 1048576; break;
        case 4: s = s4; d = d4; n = 1048576; break;
        case 5: s = s5; d = d5; n = 1048576; break;
        default: s = s6; d = d6; n = 1048576; break;
    }
    const int i = (blockIdx.x * 256 + threadIdx.x) * 8;
    if (i >= n) return;
    float4 a = *(const float4*)(s + i);
    float4 b = *(const float4*)(s + i + 4);
    short8 r;
    r[0] = (short)f2bf(a.x); r[1] = (short)f2bf(a.y);
    r[2] = (short)f2bf(a.z); r[3] = (short)f2bf(a.w);
    r[4] = (short)f2bf(b.x); r[5] = (short)f2bf(b.y);
    r[6] = (short)f2bf(b.z); r[7] = (short)f2bf(b.w);
    *(short8*)(d + i) = r;
}

// ---------------------------------------------------------------------------
// Fused QKV GEMM — 256x256 tile, BK=64, 8 waves, 8-phase schedule (T3+T4+T5).
// Fused M' = 12288 (z = mt/16 selects Q/K/V). Grid 192 = 48 mt x 4 nt,
// XCD-swizzled (192 = 8*24). LDS 128 KB: LA/LB[2 buf][8 kg][256 rows][8],
// k-major (measured conflict-free, gll-linear). Per 2 K-tiles: 8 phases,
// each = {ds_read 4-8 b128 | stage one 16KB half-tile (2 gll) | barrier |
// setprio(1) 16 MFMA setprio(0) | vmcnt(8) at odd phases | barrier}.
// Stage stream: unit j = (tile j>>2, part j&3: A03,B03,A47,B47), staged at
// phase j-6 (5-6 phase lead). vmcnt(8) uniform; tail drains 8,4,0.
// ---------------------------------------------------------------------------
__global__ __launch_bounds__(512, 2)
void gemm_qkv(const u16* __restrict__ Xq, const u16* __restrict__ Xk,
              const u16* __restrict__ Xv,
              const u16* __restrict__ Wqb, const u16* __restrict__ Wkb,
              const u16* __restrict__ Wvb,
              const float* __restrict__ bq, const float* __restrict__ bk,
              const float* __restrict__ bv,
              u16* __restrict__ Qh, u16* __restrict__ Kh, u16* __restrict__ Vth)
{
    __shared__ __align__(16) u16 LA[2][8][256][8];   // 64 KB
    __shared__ __align__(16) u16 LB[2][8][256][8];   // 64 KB

    const int bid = blockIdx.x;
    const int swz = (bid & 7) * 24 + (bid >> 3);     // bijective, 192 = 8*24
    const int mt = swz >> 2, nt = swz & 3;
    const int z  = mt >> 4;                          // 0=Q,1=K,2=V
    const int m0 = (mt & 15) * 256;                  // row within this z
    const int n0 = nt * 256;

    const u16* X = (z == 0) ? Xq : (z == 1) ? Xk : Xv;
    const u16* Wt = (z == 0) ? Wqb : (z == 1) ? Wkb : Wvb;
    const float* bias = (z == 0) ? bq : (z == 1) ? bk : bv;
    u16* out = (z == 0) ? Qh : (z == 1) ? Kh : Vth;

    const int t = threadIdx.x;
    const int w = t >> 6, l = t & 63;
    const int ln = l & 15, hi = l >> 4;
    const int wr = w >> 2, wc = w & 3;               // 2M x 4N waves

    // staging geometry: thread t loads rows (t&255), kg (t>>8)+{0,2}
    const int arow = t & 255, kgl = t >> 8;
    const size_t aoff = (size_t)(m0 + arow) * 1024 + kgl * 8;
    const size_t boff = (size_t)(n0 + arow) * 1024 + kgl * 8;

#define STAGE_A(BUF, TK0, H) { \
    GLL16(X + aoff + (TK0) + (H)*32,      &LA[BUF][(H)*4 + kgl    ][arow][0]); \
    GLL16(X + aoff + (TK0) + (H)*32 + 16, &LA[BUF][(H)*4 + kgl + 2][arow][0]); }
#define STAGE_B(BUF, TK0, H) { \
    GLL16(Wt + boff + (TK0) + (H)*32,      &LB[BUF][(H)*4 + kgl    ][arow][0]); \
    GLL16(Wt + boff + (TK0) + (H)*32 + 16, &LB[BUF][(H)*4 + kgl + 2][arow][0]); }

#define DS_AF(BUF, KS, MH) { \
    _Pragma("unroll") \
    for (int mi = 0; mi < 4; mi++) \
        af[mi] = *(const short8*)&LA[BUF][(KS)*4 + hi][wr*128 + (MH)*64 + mi*16 + ln][0]; }
#define DS_BF(BUF, KS) { \
    _Pragma("unroll") \
    for (int nj = 0; nj < 4; nj++) \
        bf[nj] = *(const short8*)&LB[BUF][(KS)*4 + hi][wc*64 + nj*16 + ln][0]; }
#define MFMA16(MH) { \
    __builtin_amdgcn_s_setprio(1); \
    _Pragma("unroll") \
    for (int mi = 0; mi < 4; mi++) \
        _Pragma("unroll") \
        for (int nj = 0; nj < 4; nj++) \
            acc[MH][mi][nj] = __builtin_amdgcn_mfma_f32_16x16x32_bf16( \
                af[mi], bf[nj], acc[MH][mi][nj], 0, 0, 0); \
    __builtin_amdgcn_s_setprio(0); }

    f32x4 acc[2][4][4];
    #pragma unroll
    for (int a = 0; a < 2; a++)
        #pragma unroll
        for (int b = 0; b < 4; b++)
            #pragma unroll
            for (int c = 0; c < 4; c++)
                acc[a][b][c] = (f32x4){0.f, 0.f, 0.f, 0.f};

    short8 af[4], bf[4];

    // prologue: units 0-5 = tile0 {A03,B03,A47,B47}, tile1 {A03,B03}
    STAGE_A(0, 0, 0); STAGE_B(0, 0, 0);
    STAGE_A(0, 0, 1); STAGE_B(0, 0, 1);
    STAGE_A(1, 64, 0); STAGE_B(1, 64, 0);
    VMW8;            // units 0,1 landed (12 outstanding -> allow 8)
    BARRIER;

    for (int it = 0; it < 7; ++it) {
        const int tk0 = it * 128;
        // p0: compute tile 2it (buf0, ks0, mh0); stage A47(2it+1)
        DS_AF(0, 0, 0); DS_BF(0, 0); STAGE_A(1, tk0 + 64, 1);
        BARRIER; MFMA16(0); BARRIER;
        // p1: (ks0, mh1); stage B47(2it+1)
        DS_AF(0, 0, 1); STAGE_B(1, tk0 + 64, 1);
        BARRIER; MFMA16(1); VMW8; BARRIER;
        // p2: (ks1, mh0); stage A03(2it+2)
        DS_AF(0, 1, 0); DS_BF(0, 1); STAGE_A(0, tk0 + 128, 0);
        BARRIER; MFMA16(0); BARRIER;
        // p3: (ks1, mh1); stage B03(2it+2)
        DS_AF(0, 1, 1); STAGE_B(0, tk0 + 128, 0);
        BARRIER; MFMA16(1); VMW8; BARRIER;
        // p4: tile 2it+1 (buf1, ks0, mh0); stage A47(2it+2)
        DS_AF(1, 0, 0); DS_BF(1, 0); STAGE_A(0, tk0 + 128, 1);
        BARRIER; MFMA16(0); BARRIER;
        // p5: (ks0, mh1); stage B47(2it+2)
        DS_AF(1, 0, 1); STAGE_B(0, tk0 + 128, 1);
        BARRIER; MFMA16(1); VMW8; BARRIER;
        // p6: (ks1, mh0); stage A03(2it+3)
        DS_AF(1, 1, 0); DS_BF(1, 1); STAGE_A(1, tk0 + 192, 0);
        BARRIER; MFMA16(0); BARRIER;
        // p7: (ks1, mh1); stage B03(2it+3)
        DS_AF(1, 1, 1); STAGE_B(1, tk0 + 192, 0);
        BARRIER; MFMA16(1); VMW8; BARRIER;
    }
    // tail: tiles 14 (buf0) and 15 (buf1); stages only at p0,p1 (units 62,63)
    {
        // p0: stage A47(15)
        DS_AF(0, 0, 0); DS_BF(0, 0); STAGE_A(1, 960, 1);
        BARRIER; MFMA16(0); BARRIER;
        // p1: stage B47(15)
        DS_AF(0, 0, 1); STAGE_B(1, 960, 1);
        BARRIER; MFMA16(1); VMW8; BARRIER;
        // p2
        DS_AF(0, 1, 0); DS_BF(0, 1);
        BARRIER; MFMA16(0); BARRIER;
        // p3
        DS_AF(0, 1, 1);
        BARRIER; MFMA16(1); VMW4; BARRIER;
        // p4
        DS_AF(1, 0, 0); DS_BF(1, 0);
        BARRIER; MFMA16(0); BARRIER;
        // p5
        DS_AF(1, 0, 1);
        BARRIER; MFMA16(1); VMW0; BARRIER;
        // p6
        DS_AF(1, 1, 0); DS_BF(1, 1);
        BARRIER; MFMA16(0); BARRIER;
        // p7
        DS_AF(1, 1, 1);
        BARRIER; MFMA16(1);
    }
#undef STAGE_A
#undef STAGE_B
#undef DS_AF
#undef DS_BF
#undef MFMA16

    // epilogue: scatter. lane holds C[row = ... + hi*4 + r][col = ... + ln]
    #pragma unroll
    for (int mh = 0; mh < 2; mh++) {
        #pragma unroll
        for (int mi = 0; mi < 4; mi++) {
            #pragma unroll
            for (int nj = 0; nj < 4; nj++) {
                const int nb = n0 + wc * 64 + nj * 16 + ln;
                const float bv2 = bias[nb];
                const int h = nb >> 6, d = nb & 63;
                #pragma unroll
                for (int r = 0; r < 4; r++) {
                    const int ml = m0 + wr * 128 + mh * 64 + mi * 16 + hi * 4 + r;
                    float v = acc[mh][mi][nj][r] + bv2;
                    if (z == 0) v *= QSCALE;
                    const int b = ml >> 11, s = ml & 2047;
                    if (z == 2)
                        out[(((size_t)(b * HH + h) * 64 + d) << 11) + s] = f2bf(v);
                    else
                        out[((((size_t)(b * HH + h)) << 11) + s) * 64 + d] = f2bf(v);
                }
            }
        }
    }
}

// ---------------------------------------------------------------------------
// Output projection GEMM, 64x128 tile, 1D grid 512 XCD-swizzled,
// double-buffered LDS (R3 structure), fp32 out + bias.
// ---------------------------------------------------------------------------
__global__ __launch_bounds__(256)
void gemm_out(const u16* __restrict__ Xb, const u16* __restrict__ Wb,
              const float* __restrict__ bias, float* __restrict__ outp)
{
    __shared__ __align__(16) u16 As[2][4][64][8];    // 8 KB
    __shared__ __align__(16) u16 Bs[2][4][128][8];   // 16 KB

    const int bid = blockIdx.x;
    const int swz = (bid & 7) * 64 + (bid >> 3);     // bijective, 512 = 8*64
    const int m0  = (swz >> 3) * 64;
    const int n0  = (swz & 7) * 128;

    const int t = threadIdx.x;
    const int w = t >> 6, l = t & 63;
    const int ln = l & 15, hi = l >> 4;
    const int wr = w >> 1, wc = w & 1;

    f32x4 acc[2][4];
    #pragma unroll
    for (int i = 0; i < 2; i++)
        #pragma unroll
        for (int j = 0; j < 4; j++)
            acc[i][j] = (f32x4){0.f, 0.f, 0.f, 0.f};

#define OSTAGE(buf, k0_)                                                     \
    {                                                                        \
        _Pragma("unroll")                                                    \
        for (int i_ = 0; i_ < 3; i_++) {                                     \
            const int id_ = w + i_ * 4;                                      \
            if (id_ < 4) {                                                   \
                const u16* gp_ = Xb + (size_t)(m0 + l) * 1024 + (k0_) + id_ * 8;\
                GLL16(gp_, &As[buf][id_][0][0]);                             \
            } else {                                                         \
                const int idb_ = id_ - 4, kg_ = idb_ & 3, half_ = idb_ >> 2; \
                const u16* gp_ = Wb + (size_t)(n0 + half_ * 64 + l) * 1024   \
                                 + (k0_) + kg_ * 8;                          \
                GLL16(gp_, &Bs[buf][kg_][half_ * 64][0]);                    \
            }                                                                \
        }                                                                    \
    }

    OSTAGE(0, 0);
    __syncthreads();
    int cur = 0;
    for (int k0 = 0; k0 < 1024; k0 += 32) {
        if (k0 + 32 < 1024) OSTAGE(cur ^ 1, k0 + 32);
        short8 af[2], bfr[4];
        #pragma unroll
        for (int mi = 0; mi < 2; mi++)
            af[mi] = *(const short8*)&As[cur][hi][wr * 32 + mi * 16 + ln][0];
        #pragma unroll
        for (int nj = 0; nj < 4; nj++)
            bfr[nj] = *(const short8*)&Bs[cur][hi][wc * 64 + nj * 16 + ln][0];
        #pragma unroll
        for (int mi = 0; mi < 2; mi++)
            #pragma unroll
            for (int nj = 0; nj < 4; nj++)
                acc[mi][nj] = __builtin_amdgcn_mfma_f32_16x16x32_bf16(
                    af[mi], bfr[nj], acc[mi][nj], 0, 0, 0);
        __syncthreads();
        cur ^= 1;
    }
#undef OSTAGE

    #pragma unroll
    for (int mi = 0; mi < 2; mi++) {
        #pragma unroll
        for (int nj = 0; nj < 4; nj++) {
            const int nb = n0 + wc * 64 + nj * 16 + ln;
            const float bv2 = bias[nb];
            #pragma unroll
            for (int r = 0; r < 4; r++) {
                const int m = m0 + wr * 32 + mi * 16 + hi * 4 + r;
                outp[(size_t)m * 1024 + nb] = acc[mi][nj][r] + bv2;
            }
        }
    }
}

// ---------------------------------------------------------------------------
// Flash attention, bf16 MFMA (unchanged).
// ---------------------------------------------------------------------------
__global__ __launch_bounds__(256)
void attn_mfma(const u16* __restrict__ Qh, const u16* __restrict__ Kh,
               const u16* __restrict__ Vt, u16* __restrict__ Cc)
{
    __shared__ __align__(16) u16 Ks[2][2][4][64][8];  // 16KB
    __shared__ __align__(16) u16 Vs[2][2][4][64][8];  // 16KB
    __shared__ __align__(16) u16 Ps[4][16][64];       // 8KB
    const int bh = blockIdx.x;
    const int y  = 31 - blockIdx.y;        // longest blocks dispatch first
    const int q0 = y * 64;
    const int t = threadIdx.x, w = t >> 6, l = t & 63;
    const int ln = l & 15, hi = l >> 4;
    const size_t base = (size_t)bh * SS * DD;
    const int qg = q0 + w * 16 + ln;

    short8 qf0, qf1;
    {
        const u16* qp = Qh + base + (size_t)qg * 64 + hi * 8;
        qf0 = *(const short8*)qp;
        qf1 = *(const short8*)(qp + 32);
    }
    f32x4 o[4];
    #pragma unroll
    for (int dj = 0; dj < 4; dj++) o[dj] = (f32x4){0.f, 0.f, 0.f, 0.f};
    float mrun = -INFINITY, lrun = 0.f;

#define STAGE(buf, key0_)                                                        \
    {                                                                            \
        _Pragma("unroll")                                                        \
        for (int i_ = 0; i_ < 4; i_++) {                                         \
            const int id_ = w + i_ * 4;                                          \
            if (id_ < 8) {                                                       \
                const int dc_ = id_ >> 2, kg_ = id_ & 3;                         \
                const u16* gp_ = Kh + base + (size_t)((key0_) + l) * 64          \
                                 + dc_ * 32 + kg_ * 8;                           \
                GLL16(gp_, &Ks[buf][dc_][kg_][0][0]);                            \
            } else {                                                             \
                const int kc_ = (id_ >> 2) & 1, kg_ = id_ & 3;                   \
                const u16* gp_ = Vt + base + (size_t)l * SS + (key0_)            \
                                 + kc_ * 32 + kg_ * 8;                           \
                GLL16(gp_, &Vs[buf][kc_][kg_][0][0]);                            \
            }                                                                    \
        }                                                                        \
    }

    STAGE(0, 0);
    __syncthreads();
    int cur = 0;
    const int nkt = y + 1;
    for (int kt = 0; kt < nkt; kt++) {
        const int key0 = kt * 64;
        if (kt + 1 < nkt) STAGE(cur ^ 1, key0 + 64);

        f32x4 st[4];
        #pragma unroll
        for (int kt4 = 0; kt4 < 4; kt4++) {
            short8 ka = *(const short8*)&Ks[cur][0][hi][kt4 * 16 + ln][0];
            short8 kb = *(const short8*)&Ks[cur][1][hi][kt4 * 16 + ln][0];
            f32x4 zz = (f32x4){0.f, 0.f, 0.f, 0.f};
            zz = __builtin_amdgcn_mfma_f32_16x16x32_bf16(ka, qf0, zz, 0, 0, 0);
            zz = __builtin_amdgcn_mfma_f32_16x16x32_bf16(kb, qf1, zz, 0, 0, 0);
            st[kt4] = zz;
        }
        if (kt == y) {
            #pragma unroll
            for (int kt4 = 0; kt4 < 4; kt4++)
                #pragma unroll
                for (int r = 0; r < 4; r++)
                    if (key0 + kt4 * 16 + hi * 4 + r > qg)
                        st[kt4][r] = -INFINITY;
        }

        float tmax = -INFINITY;
        #pragma unroll
        for (int kt4 = 0; kt4 < 4; kt4++)
            #pragma unroll
            for (int r = 0; r < 4; r++)
                tmax = fmaxf(tmax, st[kt4][r]);
        tmax = fmaxf(tmax, __shfl_xor(tmax, 16));
        tmax = fmaxf(tmax, __shfl_xor(tmax, 32));
        if (__ballot(tmax > mrun + 8.f)) {      // deferred-max rescale (T13)
            const float mnew = fmaxf(mrun, tmax);
            const float alpha = exp2_fast(mrun - mnew);
            lrun *= alpha;
            mrun = mnew;
            #pragma unroll
            for (int r = 0; r < 4; r++) {
                const float ar = __shfl(alpha, hi * 4 + r);
                #pragma unroll
                for (int dj = 0; dj < 4; dj++) o[dj][r] *= ar;
            }
        }
        float p[4][4];
        float lsum = 0.f;
        #pragma unroll
        for (int kt4 = 0; kt4 < 4; kt4++)
            #pragma unroll
            for (int r = 0; r < 4; r++) {
                p[kt4][r] = exp2_fast(st[kt4][r] - mrun);
                lsum += p[kt4][r];
            }
        lsum += __shfl_xor(lsum, 16);
        lsum += __shfl_xor(lsum, 32);
        lrun += lsum;

        char* prow = ((char*)Ps) + (w * 16 + ln) * 128 + (hi & 1) * 8;
        #pragma unroll
        for (int kt4 = 0; kt4 < 4; kt4++) {
            unsigned dw0, dw1;
            asm("v_cvt_pk_bf16_f32 %0, %1, %2" : "=v"(dw0)
                : "v"(p[kt4][0]), "v"(p[kt4][1]));
            asm("v_cvt_pk_bf16_f32 %0, %1, %2" : "=v"(dw1)
                : "v"(p[kt4][2]), "v"(p[kt4][3]));
            const int g = (2 * kt4 + (hi >> 1)) ^ (ln & 7);
            *(uint2*)(prow + g * 16) = make_uint2(dw0, dw1);
        }

        #pragma unroll
        for (int kc = 0; kc < 2; kc++) {
            const int gr = (kc * 4 + hi) ^ (ln & 7);
            short8 pa = *(const short8*)(((char*)Ps) + (w * 16 + ln) * 128 + gr * 16);
            #pragma unroll
            for (int dj = 0; dj < 4; dj++) {
                short8 vb = *(const short8*)&Vs[cur][kc][hi][dj * 16 + ln][0];
                o[dj] = __builtin_amdgcn_mfma_f32_16x16x32_bf16(pa, vb, o[dj], 0, 0, 0);
            }
        }
        __syncthreads();
        cur ^= 1;
    }
#undef STAGE

    const float inv = 1.f / lrun;
    #pragma unroll
    for (int r = 0; r < 4; r++) {
        const float ir = __shfl(inv, hi * 4 + r);
        const int s = q0 + w * 16 + hi * 4 + r;
        const size_t ob = ((size_t)(bh >> 4) * SS + s) * EE + (bh & 15) * 64;
        #pragma unroll
        for (int dj = 0; dj < 4; dj++)
            Cc[ob + dj * 16 + ln] = f2bf(o[dj][r] * ir);
    }
}

extern "C" void kernel_launch(void* const* d_in, const int* in_sizes, int n_in,
                              void* d_out, int out_size, void* d_ws, size_t ws_size,
                              hipStream_t stream)
{
    (void)in_sizes; (void)n_in; (void)out_size; (void)ws_size;
    const float* query = (const float*)d_in[0];
    const float* key   = (const float*)d_in[1];
    const float* value = (const float*)d_in[2];
    // d_in[3] = mask: exactly causal tril, implemented analytically
    const float* Wq = (const float*)d_in[4];
    const float* bq = (const float*)d_in[5];
    const float* Wk = (const float*)d_in[6];
    const float* bk = (const float*)d_in[7];
    const float* Wv = (const float*)d_in[8];
    const float* bv = (const float*)d_in[9];
    const float* Wo = (const float*)d_in[10];
    const float* bo = (const float*)d_in[11];
    float* out = (float*)d_out;

    char* ws = (char*)d_ws;
    u16* Xq = (u16*)(ws);                         // 8 MiB
    u16* Xk = (u16*)(ws + 8388608);               // 8 MiB
    u16* Xv = (u16*)(ws + 16777216);              // 8 MiB
    u16* Wqb = (u16*)(ws + 25165824);             // 2 MiB
    u16* Wkb = (u16*)(ws + 27262976);             // 2 MiB
    u16* Wvb = (u16*)(ws + 29360128);             // 2 MiB
    u16* Wob = (u16*)(ws + 31457280);             // 2 MiB
    u16* Qh  = (u16*)(ws + 33554432);             // 8 MiB [b,h][s][d]
    u16* Kh  = (u16*)(ws + 41943040);             // 8 MiB [b,h][s][d]
    u16* Vth = (u16*)(ws + 50331648);             // 8 MiB [b,h][d][s]
    u16* Cc  = (u16*)(ws + 58720256);             // 8 MiB [b][s][e]

    cvt_bf16<<<dim3(2048, 7), 256, 0, stream>>>(
        query, key, value, Wq, Wk, Wv, Wo,
        Xq, Xk, Xv, Wqb, Wkb, Wvb, Wob);

    gemm_qkv<<<192, 512, 0, stream>>>(
        Xq, Xk, Xv, Wqb, Wkb, Wvb, bq, bk, bv, Qh, Kh, Vth);
    attn_mfma<<<dim3(32, 32), 256, 0, stream>>>(Qh, Kh, Vth, Cc);
    gemm_out<<<512, 256, 0, stream>>>(Cc, Wob, bo, out);
}

// Round 7
// 146.000 us; speedup vs baseline: 1.1181x; 1.1133x over previous
//
#include <hip/hip_runtime.h>
#include <math.h>

#define BB 2
#define SS 2048
#define EE 1024
#define HH 16
#define DD 64

typedef unsigned short u16;
typedef __attribute__((ext_vector_type(8))) short short8;
typedef __attribute__((ext_vector_type(4))) float f32x4;

__device__ __forceinline__ u16 f2bf(float x) {
    union { float f; unsigned u; } v; v.f = x;
    return (u16)((v.u + 0x7fffu + ((v.u >> 16) & 1u)) >> 16);
}

__device__ __forceinline__ float exp2_fast(float x) {
    float r;
    asm("v_exp_f32 %0, %1" : "=v"(r) : "v"(x));
    return r;
}

#define GLL16(gp, lp) \
    __builtin_amdgcn_global_load_lds( \
        (const __attribute__((address_space(1))) void*)(gp), \
        (__attribute__((address_space(3))) void*)(lp), 16, 0, 0)

#define BARRIER do { asm volatile("" ::: "memory"); \
                     __builtin_amdgcn_s_barrier();  \
                     asm volatile("" ::: "memory"); } while (0)
#define VMW8 asm volatile("s_waitcnt vmcnt(8)" ::: "memory")
#define VMW4 asm volatile("s_waitcnt vmcnt(4)" ::: "memory")
#define VMW0 asm volatile("s_waitcnt vmcnt(0)" ::: "memory")

// QSCALE = (1/sqrt(64)) * log2(e): softmax computed in base-2
#define QSCALE 0.18033688f

// ---------------------------------------------------------------------------
// fp32 -> bf16 conversion
// ---------------------------------------------------------------------------
__global__ __launch_bounds__(256)
void cvt_bf16(const float* __restrict__ s0, const float* __restrict__ s1,
              const float* __restrict__ s2, const float* __restrict__ s3,
              const float* __restrict__ s4, const float* __restrict__ s5,
              const float* __restrict__ s6,
              u16* __restrict__ d0, u16* __restrict__ d1, u16* __restrict__ d2,
              u16* __restrict__ d3, u16* __restrict__ d4, u16* __restrict__ d5,
              u16* __restrict__ d6)
{
    const int z = blockIdx.y;
    const float* s; u16* d; int n;
    switch (z) {
        case 0: s = s0; d = d0; n = 4194304; break;
        case 1: s = s1; d = d1; n = 4194304; break;
        case 2: s = s2; d = d2; n = 4194304; break;
        case 3: s = s3; d = d3; n = 1048576; break;
        case 4: s = s4; d = d4; n = 1048576; break;
        case 5: s = s5; d = d5; n = 1048576; break;
        default: s = s6; d = d6; n = 1048576; break;
    }
    const int i = (blockIdx.x * 256 + threadIdx.x) * 8;
    if (i >= n) return;
    float4 a = *(const float4*)(s + i);
    float4 b = *(const float4*)(s + i + 4);
    short8 r;
    r[0] = (short)f2bf(a.x); r[1] = (short)f2bf(a.y);
    r[2] = (short)f2bf(a.z); r[3] = (short)f2bf(a.w);
    r[4] = (short)f2bf(b.x); r[5] = (short)f2bf(b.y);
    r[6] = (short)f2bf(b.z); r[7] = (short)f2bf(b.w);
    *(short8*)(d + i) = r;
}

// ---------------------------------------------------------------------------
// Fused QKV GEMM — 256x256 tile, BK=64, 8 waves, 8-phase schedule.
// R6 skeleton unchanged; staging rewritten for COALESCED global reads:
// LDS = [buf][khalf][256 rows][32k] (64B rows, each 16KB unit contiguous).
// Stage instr covers 16 full rows contiguously (16 lines/instr vs 64 before).
// XOR swizzle gp = gl ^ (row&3) applied on the GLOBAL source (LDS dest stays
// lane-linear, G21); ds_read uses granule hi ^ (ln&3) -> b128 bank floor.
// Unit stream/liveness/vmcnt identical to R6 (unit (buf,khalf) dead after its
// ks phases, 4-phase staging lead, VMW8 at odd phases, tail drains 8,4,0).
// ---------------------------------------------------------------------------
__global__ __launch_bounds__(512, 2)
void gemm_qkv(const u16* __restrict__ Xq, const u16* __restrict__ Xk,
              const u16* __restrict__ Xv,
              const u16* __restrict__ Wqb, const u16* __restrict__ Wkb,
              const u16* __restrict__ Wvb,
              const float* __restrict__ bq, const float* __restrict__ bk,
              const float* __restrict__ bv,
              u16* __restrict__ Qh, u16* __restrict__ Kh, u16* __restrict__ Vth)
{
    __shared__ __align__(16) u16 LA[2][2][256][32];   // 64 KB
    __shared__ __align__(16) u16 LB[2][2][256][32];   // 64 KB

    const int bid = blockIdx.x;
    const int swz = (bid & 7) * 24 + (bid >> 3);     // bijective, 192 = 8*24
    const int mt = swz >> 2, nt = swz & 3;
    const int z  = mt >> 4;                          // 0=Q,1=K,2=V
    const int m0 = (mt & 15) * 256;                  // row within this z
    const int n0 = nt * 256;

    const u16* X = (z == 0) ? Xq : (z == 1) ? Xk : Xv;
    const u16* Wt = (z == 0) ? Wqb : (z == 1) ? Wkb : Wvb;
    const float* bias = (z == 0) ? bq : (z == 1) ? bk : bv;
    u16* out = (z == 0) ? Qh : (z == 1) ? Kh : Vth;

    const int t = threadIdx.x;
    const int w = t >> 6, l = t & 63;
    const int ln = l & 15, hi = l >> 4;
    const int wr = w >> 2, wc = w & 3;               // 2M x 4N waves

    // coalesced staging geometry: gll #i of thread t writes unit byte
    // i*8192 + t*16  ->  row = i*128 + (t>>2), phys granule gp = t&3.
    // source granule gl = gp ^ (row&3)  (row&3 == (t>>2)&3 for both i).
    const int arow0 = t >> 2, gp4 = t & 3;
    const int gl4   = gp4 ^ (arow0 & 3);
    const size_t aoff0 = (size_t)(m0 + arow0) * 1024 + gl4 * 8;
    const size_t aoff1 = (size_t)(m0 + 128 + arow0) * 1024 + gl4 * 8;
    const size_t boff0 = (size_t)(n0 + arow0) * 1024 + gl4 * 8;
    const size_t boff1 = (size_t)(n0 + 128 + arow0) * 1024 + gl4 * 8;

#define STAGE_A(BUF, TK0, H) { \
    GLL16(X + aoff0 + (TK0) + (H)*32, &LA[BUF][H][arow0      ][gp4*8]); \
    GLL16(X + aoff1 + (TK0) + (H)*32, &LA[BUF][H][arow0 + 128][gp4*8]); }
#define STAGE_B(BUF, TK0, H) { \
    GLL16(Wt + boff0 + (TK0) + (H)*32, &LB[BUF][H][arow0      ][gp4*8]); \
    GLL16(Wt + boff1 + (TK0) + (H)*32, &LB[BUF][H][arow0 + 128][gp4*8]); }

#define DS_AF(BUF, KS, MH) { \
    _Pragma("unroll") \
    for (int mi = 0; mi < 4; mi++) \
        af[mi] = *(const short8*)&LA[BUF][KS][wr*128 + (MH)*64 + mi*16 + ln][(hi ^ (ln & 3))*8]; }
#define DS_BF(BUF, KS) { \
    _Pragma("unroll") \
    for (int nj = 0; nj < 4; nj++) \
        bf[nj] = *(const short8*)&LB[BUF][KS][wc*64 + nj*16 + ln][(hi ^ (ln & 3))*8]; }
#define MFMA16(MH) { \
    __builtin_amdgcn_s_setprio(1); \
    _Pragma("unroll") \
    for (int mi = 0; mi < 4; mi++) \
        _Pragma("unroll") \
        for (int nj = 0; nj < 4; nj++) \
            acc[MH][mi][nj] = __builtin_amdgcn_mfma_f32_16x16x32_bf16( \
                af[mi], bf[nj], acc[MH][mi][nj], 0, 0, 0); \
    __builtin_amdgcn_s_setprio(0); }

    f32x4 acc[2][4][4];
    #pragma unroll
    for (int a = 0; a < 2; a++)
        #pragma unroll
        for (int b = 0; b < 4; b++)
            #pragma unroll
            for (int c = 0; c < 4; c++)
                acc[a][b][c] = (f32x4){0.f, 0.f, 0.f, 0.f};

    short8 af[4], bf[4];

    // prologue: units 0-5 = tile0 {Alo,Blo,Ahi,Bhi}, tile1 {Alo,Blo}
    STAGE_A(0, 0, 0); STAGE_B(0, 0, 0);
    STAGE_A(0, 0, 1); STAGE_B(0, 0, 1);
    STAGE_A(1, 64, 0); STAGE_B(1, 64, 0);
    VMW8;            // units 0,1 (tile0 lo-halves) landed
    BARRIER;

    for (int it = 0; it < 7; ++it) {
        const int tk0 = it * 128;
        // p0: compute tile 2it (buf0, ks0, mh0); stage A-hi(2it+1)
        DS_AF(0, 0, 0); DS_BF(0, 0); STAGE_A(1, tk0 + 64, 1);
        BARRIER; MFMA16(0); BARRIER;
        // p1: (ks0, mh1); stage B-hi(2it+1)
        DS_AF(0, 0, 1); STAGE_B(1, tk0 + 64, 1);
        BARRIER; MFMA16(1); VMW8; BARRIER;
        // p2: (ks1, mh0); stage A-lo(2it+2)
        DS_AF(0, 1, 0); DS_BF(0, 1); STAGE_A(0, tk0 + 128, 0);
        BARRIER; MFMA16(0); BARRIER;
        // p3: (ks1, mh1); stage B-lo(2it+2)
        DS_AF(0, 1, 1); STAGE_B(0, tk0 + 128, 0);
        BARRIER; MFMA16(1); VMW8; BARRIER;
        // p4: tile 2it+1 (buf1, ks0, mh0); stage A-hi(2it+2)
        DS_AF(1, 0, 0); DS_BF(1, 0); STAGE_A(0, tk0 + 128, 1);
        BARRIER; MFMA16(0); BARRIER;
        // p5: (ks0, mh1); stage B-hi(2it+2)
        DS_AF(1, 0, 1); STAGE_B(0, tk0 + 128, 1);
        BARRIER; MFMA16(1); VMW8; BARRIER;
        // p6: (ks1, mh0); stage A-lo(2it+3)
        DS_AF(1, 1, 0); DS_BF(1, 1); STAGE_A(1, tk0 + 192, 0);
        BARRIER; MFMA16(0); BARRIER;
        // p7: (ks1, mh1); stage B-lo(2it+3)
        DS_AF(1, 1, 1); STAGE_B(1, tk0 + 192, 0);
        BARRIER; MFMA16(1); VMW8; BARRIER;
    }
    // tail: tiles 14 (buf0) and 15 (buf1)
    {
        DS_AF(0, 0, 0); DS_BF(0, 0); STAGE_A(1, 960, 1);
        BARRIER; MFMA16(0); BARRIER;
        DS_AF(0, 0, 1); STAGE_B(1, 960, 1);
        BARRIER; MFMA16(1); VMW8; BARRIER;
        DS_AF(0, 1, 0); DS_BF(0, 1);
        BARRIER; MFMA16(0); BARRIER;
        DS_AF(0, 1, 1);
        BARRIER; MFMA16(1); VMW4; BARRIER;
        DS_AF(1, 0, 0); DS_BF(1, 0);
        BARRIER; MFMA16(0); BARRIER;
        DS_AF(1, 0, 1);
        BARRIER; MFMA16(1); VMW0; BARRIER;
        DS_AF(1, 1, 0); DS_BF(1, 1);
        BARRIER; MFMA16(0); BARRIER;
        DS_AF(1, 1, 1);
        BARRIER; MFMA16(1);
    }
#undef STAGE_A
#undef STAGE_B
#undef DS_AF
#undef DS_BF
#undef MFMA16

    // epilogue: scatter. lane holds C[row = ... + hi*4 + r][col = ... + ln]
    #pragma unroll
    for (int mh = 0; mh < 2; mh++) {
        #pragma unroll
        for (int mi = 0; mi < 4; mi++) {
            #pragma unroll
            for (int nj = 0; nj < 4; nj++) {
                const int nb = n0 + wc * 64 + nj * 16 + ln;
                const float bv2 = bias[nb];
                const int h = nb >> 6, d = nb & 63;
                #pragma unroll
                for (int r = 0; r < 4; r++) {
                    const int ml = m0 + wr * 128 + mh * 64 + mi * 16 + hi * 4 + r;
                    float v = acc[mh][mi][nj][r] + bv2;
                    if (z == 0) v *= QSCALE;
                    const int b = ml >> 11, s = ml & 2047;
                    if (z == 2)
                        out[(((size_t)(b * HH + h) * 64 + d) << 11) + s] = f2bf(v);
                    else
                        out[((((size_t)(b * HH + h)) << 11) + s) * 64 + d] = f2bf(v);
                }
            }
        }
    }
}

// ---------------------------------------------------------------------------
// Output projection GEMM, 64x128 tile, 1D grid 512 XCD-swizzled, 2-phase
// dbuf; staging coalesced (row-major 64B rows + source XOR swizzle).
// ---------------------------------------------------------------------------
__global__ __launch_bounds__(256)
void gemm_out(const u16* __restrict__ Xb, const u16* __restrict__ Wb,
              const float* __restrict__ bias, float* __restrict__ outp)
{
    __shared__ __align__(16) u16 As[2][64][32];    // 4 KB / buf
    __shared__ __align__(16) u16 Bs[2][128][32];   // 8 KB / buf

    const int bid = blockIdx.x;
    const int swz = (bid & 7) * 64 + (bid >> 3);     // bijective, 512 = 8*64
    const int m0  = (swz >> 3) * 64;
    const int n0  = (swz & 7) * 128;

    const int t = threadIdx.x;
    const int w = t >> 6, l = t & 63;
    const int ln = l & 15, hi = l >> 4;
    const int wr = w >> 1, wc = w & 1;

    const int row0 = t >> 2, gp4 = t & 3;
    const int gl4  = gp4 ^ (row0 & 3);

    f32x4 acc[2][4];
    #pragma unroll
    for (int i = 0; i < 2; i++)
        #pragma unroll
        for (int j = 0; j < 4; j++)
            acc[i][j] = (f32x4){0.f, 0.f, 0.f, 0.f};

#define OSTAGE(buf, k0_) { \
    GLL16(Xb + (size_t)(m0 + row0) * 1024 + (k0_) + gl4 * 8,        \
          &As[buf][row0][gp4 * 8]);                                  \
    GLL16(Wb + (size_t)(n0 + row0) * 1024 + (k0_) + gl4 * 8,        \
          &Bs[buf][row0][gp4 * 8]);                                  \
    GLL16(Wb + (size_t)(n0 + 64 + row0) * 1024 + (k0_) + gl4 * 8,   \
          &Bs[buf][row0 + 64][gp4 * 8]); }

    OSTAGE(0, 0);
    __syncthreads();
    int cur = 0;
    for (int k0 = 0; k0 < 1024; k0 += 32) {
        if (k0 + 32 < 1024) OSTAGE(cur ^ 1, k0 + 32);
        short8 af[2], bfr[4];
        #pragma unroll
        for (int mi = 0; mi < 2; mi++)
            af[mi] = *(const short8*)&As[cur][wr*32 + mi*16 + ln][(hi ^ (ln & 3))*8];
        #pragma unroll
        for (int nj = 0; nj < 4; nj++)
            bfr[nj] = *(const short8*)&Bs[cur][wc*64 + nj*16 + ln][(hi ^ (ln & 3))*8];
        #pragma unroll
        for (int mi = 0; mi < 2; mi++)
            #pragma unroll
            for (int nj = 0; nj < 4; nj++)
                acc[mi][nj] = __builtin_amdgcn_mfma_f32_16x16x32_bf16(
                    af[mi], bfr[nj], acc[mi][nj], 0, 0, 0);
        __syncthreads();
        cur ^= 1;
    }
#undef OSTAGE

    #pragma unroll
    for (int mi = 0; mi < 2; mi++) {
        #pragma unroll
        for (int nj = 0; nj < 4; nj++) {
            const int nb = n0 + wc * 64 + nj * 16 + ln;
            const float bv2 = bias[nb];
            #pragma unroll
            for (int r = 0; r < 4; r++) {
                const int m = m0 + wr * 32 + mi * 16 + hi * 4 + r;
                outp[(size_t)m * 1024 + nb] = acc[mi][nj][r] + bv2;
            }
        }
    }
}

// ---------------------------------------------------------------------------
// Flash attention, bf16 MFMA (unchanged from R3).
// ---------------------------------------------------------------------------
__global__ __launch_bounds__(256)
void attn_mfma(const u16* __restrict__ Qh, const u16* __restrict__ Kh,
               const u16* __restrict__ Vt, u16* __restrict__ Cc)
{
    __shared__ __align__(16) u16 Ks[2][2][4][64][8];  // 16KB
    __shared__ __align__(16) u16 Vs[2][2][4][64][8];  // 16KB
    __shared__ __align__(16) u16 Ps[4][16][64];       // 8KB
    const int bh = blockIdx.x;
    const int y  = 31 - blockIdx.y;        // longest blocks dispatch first
    const int q0 = y * 64;
    const int t = threadIdx.x, w = t >> 6, l = t & 63;
    const int ln = l & 15, hi = l >> 4;
    const size_t base = (size_t)bh * SS * DD;
    const int qg = q0 + w * 16 + ln;

    short8 qf0, qf1;
    {
        const u16* qp = Qh + base + (size_t)qg * 64 + hi * 8;
        qf0 = *(const short8*)qp;
        qf1 = *(const short8*)(qp + 32);
    }
    f32x4 o[4];
    #pragma unroll
    for (int dj = 0; dj < 4; dj++) o[dj] = (f32x4){0.f, 0.f, 0.f, 0.f};
    float mrun = -INFINITY, lrun = 0.f;

#define STAGE(buf, key0_)                                                        \
    {                                                                            \
        _Pragma("unroll")                                                        \
        for (int i_ = 0; i_ < 4; i_++) {                                         \
            const int id_ = w + i_ * 4;                                          \
            if (id_ < 8) {                                                       \
                const int dc_ = id_ >> 2, kg_ = id_ & 3;                         \
                const u16* gp_ = Kh + base + (size_t)((key0_) + l) * 64          \
                                 + dc_ * 32 + kg_ * 8;                           \
                GLL16(gp_, &Ks[buf][dc_][kg_][0][0]);                            \
            } else {                                                             \
                const int kc_ = (id_ >> 2) & 1, kg_ = id_ & 3;                   \
                const u16* gp_ = Vt + base + (size_t)l * SS + (key0_)            \
                                 + kc_ * 32 + kg_ * 8;                           \
                GLL16(gp_, &Vs[buf][kc_][kg_][0][0]);                            \
            }                                                                    \
        }                                                                        \
    }

    STAGE(0, 0);
    __syncthreads();
    int cur = 0;
    const int nkt = y + 1;
    for (int kt = 0; kt < nkt; kt++) {
        const int key0 = kt * 64;
        if (kt + 1 < nkt) STAGE(cur ^ 1, key0 + 64);

        f32x4 st[4];
        #pragma unroll
        for (int kt4 = 0; kt4 < 4; kt4++) {
            short8 ka = *(const short8*)&Ks[cur][0][hi][kt4 * 16 + ln][0];
            short8 kb = *(const short8*)&Ks[cur][1][hi][kt4 * 16 + ln][0];
            f32x4 zz = (f32x4){0.f, 0.f, 0.f, 0.f};
            zz = __builtin_amdgcn_mfma_f32_16x16x32_bf16(ka, qf0, zz, 0, 0, 0);
            zz = __builtin_amdgcn_mfma_f32_16x16x32_bf16(kb, qf1, zz, 0, 0, 0);
            st[kt4] = zz;
        }
        if (kt == y) {
            #pragma unroll
            for (int kt4 = 0; kt4 < 4; kt4++)
                #pragma unroll
                for (int r = 0; r < 4; r++)
                    if (key0 + kt4 * 16 + hi * 4 + r > qg)
                        st[kt4][r] = -INFINITY;
        }

        float tmax = -INFINITY;
        #pragma unroll
        for (int kt4 = 0; kt4 < 4; kt4++)
            #pragma unroll
            for (int r = 0; r < 4; r++)
                tmax = fmaxf(tmax, st[kt4][r]);
        tmax = fmaxf(tmax, __shfl_xor(tmax, 16));
        tmax = fmaxf(tmax, __shfl_xor(tmax, 32));
        if (__ballot(tmax > mrun + 8.f)) {      // deferred-max rescale (T13)
            const float mnew = fmaxf(mrun, tmax);
            const float alpha = exp2_fast(mrun - mnew);
            lrun *= alpha;
            mrun = mnew;
            #pragma unroll
            for (int r = 0; r < 4; r++) {
                const float ar = __shfl(alpha, hi * 4 + r);
                #pragma unroll
                for (int dj = 0; dj < 4; dj++) o[dj][r] *= ar;
            }
        }
        float p[4][4];
        float lsum = 0.f;
        #pragma unroll
        for (int kt4 = 0; kt4 < 4; kt4++)
            #pragma unroll
            for (int r = 0; r < 4; r++) {
                p[kt4][r] = exp2_fast(st[kt4][r] - mrun);
                lsum += p[kt4][r];
            }
        lsum += __shfl_xor(lsum, 16);
        lsum += __shfl_xor(lsum, 32);
        lrun += lsum;

        char* prow = ((char*)Ps) + (w * 16 + ln) * 128 + (hi & 1) * 8;
        #pragma unroll
        for (int kt4 = 0; kt4 < 4; kt4++) {
            unsigned dw0, dw1;
            asm("v_cvt_pk_bf16_f32 %0, %1, %2" : "=v"(dw0)
                : "v"(p[kt4][0]), "v"(p[kt4][1]));
            asm("v_cvt_pk_bf16_f32 %0, %1, %2" : "=v"(dw1)
                : "v"(p[kt4][2]), "v"(p[kt4][3]));
            const int g = (2 * kt4 + (hi >> 1)) ^ (ln & 7);
            *(uint2*)(prow + g * 16) = make_uint2(dw0, dw1);
        }

        #pragma unroll
        for (int kc = 0; kc < 2; kc++) {
            const int gr = (kc * 4 + hi) ^ (ln & 7);
            short8 pa = *(const short8*)(((char*)Ps) + (w * 16 + ln) * 128 + gr * 16);
            #pragma unroll
            for (int dj = 0; dj < 4; dj++) {
                short8 vb = *(const short8*)&Vs[cur][kc][hi][dj * 16 + ln][0];
                o[dj] = __builtin_amdgcn_mfma_f32_16x16x32_bf16(pa, vb, o[dj], 0, 0, 0);
            }
        }
        __syncthreads();
        cur ^= 1;
    }
#undef STAGE

    const float inv = 1.f / lrun;
    #pragma unroll
    for (int r = 0; r < 4; r++) {
        const float ir = __shfl(inv, hi * 4 + r);
        const int s = q0 + w * 16 + hi * 4 + r;
        const size_t ob = ((size_t)(bh >> 4) * SS + s) * EE + (bh & 15) * 64;
        #pragma unroll
        for (int dj = 0; dj < 4; dj++)
            Cc[ob + dj * 16 + ln] = f2bf(o[dj][r] * ir);
    }
}

extern "C" void kernel_launch(void* const* d_in, const int* in_sizes, int n_in,
                              void* d_out, int out_size, void* d_ws, size_t ws_size,
                              hipStream_t stream)
{
    (void)in_sizes; (void)n_in; (void)out_size; (void)ws_size;
    const float* query = (const float*)d_in[0];
    const float* key   = (const float*)d_in[1];
    const float* value = (const float*)d_in[2];
    // d_in[3] = mask: exactly causal tril, implemented analytically
    const float* Wq = (const float*)d_in[4];
    const float* bq = (const float*)d_in[5];
    const float* Wk = (const float*)d_in[6];
    const float* bk = (const float*)d_in[7];
    const float* Wv = (const float*)d_in[8];
    const float* bv = (const float*)d_in[9];
    const float* Wo = (const float*)d_in[10];
    const float* bo = (const float*)d_in[11];
    float* out = (float*)d_out;

    char* ws = (char*)d_ws;
    u16* Xq = (u16*)(ws);                         // 8 MiB
    u16* Xk = (u16*)(ws + 8388608);               // 8 MiB
    u16* Xv = (u16*)(ws + 16777216);              // 8 MiB
    u16* Wqb = (u16*)(ws + 25165824);             // 2 MiB
    u16* Wkb = (u16*)(ws + 27262976);             // 2 MiB
    u16* Wvb = (u16*)(ws + 29360128);             // 2 MiB
    u16* Wob = (u16*)(ws + 31457280);             // 2 MiB
    u16* Qh  = (u16*)(ws + 33554432);             // 8 MiB [b,h][s][d]
    u16* Kh  = (u16*)(ws + 41943040);             // 8 MiB [b,h][s][d]
    u16* Vth = (u16*)(ws + 50331648);             // 8 MiB [b,h][d][s]
    u16* Cc  = (u16*)(ws + 58720256);             // 8 MiB [b][s][e]

    cvt_bf16<<<dim3(2048, 7), 256, 0, stream>>>(
        query, key, value, Wq, Wk, Wv, Wo,
        Xq, Xk, Xv, Wqb, Wkb, Wvb, Wob);

    gemm_qkv<<<192, 512, 0, stream>>>(
        Xq, Xk, Xv, Wqb, Wkb, Wvb, bq, bk, bv, Qh, Kh, Vth);
    attn_mfma<<<dim3(32, 32), 256, 0, stream>>>(Qh, Kh, Vth, Cc);
    gemm_out<<<512, 256, 0, stream>>>(Cc, Wob, bo, out);
}

// Round 8
// 140.011 us; speedup vs baseline: 1.1660x; 1.0428x over previous
//
#include <hip/hip_runtime.h>
#include <math.h>

#define BB 2
#define SS 2048
#define EE 1024
#define HH 16
#define DD 64

typedef unsigned short u16;
typedef __attribute__((ext_vector_type(8))) short short8;
typedef __attribute__((ext_vector_type(4))) float f32x4;

__device__ __forceinline__ u16 f2bf(float x) {
    union { float f; unsigned u; } v; v.f = x;
    return (u16)((v.u + 0x7fffu + ((v.u >> 16) & 1u)) >> 16);
}

__device__ __forceinline__ float exp2_fast(float x) {
    float r;
    asm("v_exp_f32 %0, %1" : "=v"(r) : "v"(x));
    return r;
}

#define GLL16(gp, lp) \
    __builtin_amdgcn_global_load_lds( \
        (const __attribute__((address_space(1))) void*)(gp), \
        (__attribute__((address_space(3))) void*)(lp), 16, 0, 0)

// QSCALE = (1/sqrt(64)) * log2(e): softmax computed in base-2
#define QSCALE 0.18033688f

// ---------------------------------------------------------------------------
// fp32 -> bf16 conversion — WEIGHTS ONLY now (activations fused into gemm).
// ---------------------------------------------------------------------------
__global__ __launch_bounds__(256)
void cvt_bf16(const float* __restrict__ s0, const float* __restrict__ s1,
              const float* __restrict__ s2, const float* __restrict__ s3,
              u16* __restrict__ d0, u16* __restrict__ d1,
              u16* __restrict__ d2, u16* __restrict__ d3)
{
    const int z = blockIdx.y;
    const float* s; u16* d;
    switch (z) {
        case 0: s = s0; d = d0; break;
        case 1: s = s1; d = d1; break;
        case 2: s = s2; d = d2; break;
        default: s = s3; d = d3; break;
    }
    const int i = (blockIdx.x * 256 + threadIdx.x) * 8;   // n = 1048576
    float4 a = *(const float4*)(s + i);
    float4 b = *(const float4*)(s + i + 4);
    short8 r;
    r[0] = (short)f2bf(a.x); r[1] = (short)f2bf(a.y);
    r[2] = (short)f2bf(a.z); r[3] = (short)f2bf(a.w);
    r[4] = (short)f2bf(b.x); r[5] = (short)f2bf(b.y);
    r[6] = (short)f2bf(b.z); r[7] = (short)f2bf(b.w);
    *(short8*)(d + i) = r;
}

// ---------------------------------------------------------------------------
// Fused QKV GEMM with in-kernel fp32->bf16 A-staging (cvt fused, T14 split).
// 128x128 tile, BK=32, 256 thr = 4 waves, 3 blocks/CU. Grid 768 = 8*96
// XCD-swizzled. A: fp32 global -> regs (deep pipeline, original input
// buffers) -> f2bf -> ds_write_b128, XOR granule swizzle on BOTH sides.
// B (bf16 weights, L2-resident): global_load_lds, source-XOR swizzle.
// Per iter: {issue B gll + A loads for it+1} {ds_read frags(it), 16 MFMA}
// {cvt+write A(it+1)} __syncthreads (drain already-consumed loads).
// z=0: Q scatter [b,h][s][d] scaled QSCALE; z=1: K scatter; z=2: V transposed.
// ---------------------------------------------------------------------------
__global__ __launch_bounds__(256, 3)
void gemm_qkv(const float* __restrict__ Xq, const float* __restrict__ Xk,
              const float* __restrict__ Xv,
              const u16* __restrict__ Wqb, const u16* __restrict__ Wkb,
              const u16* __restrict__ Wvb,
              const float* __restrict__ bq, const float* __restrict__ bk,
              const float* __restrict__ bv,
              u16* __restrict__ Qh, u16* __restrict__ Kh, u16* __restrict__ Vth)
{
    __shared__ __align__(16) u16 LA[2][128][32];   // 8 KB / buf, 64B rows
    __shared__ __align__(16) u16 LB[2][128][32];   // 8 KB / buf

    const int bid = blockIdx.x;
    const int swz = (bid & 7) * 96 + (bid >> 3);   // bijective, 768 = 8*96
    const int z   = swz >> 8;                      // 0=Q,1=K,2=V
    const int rem = swz & 255;
    const int m0  = (rem >> 3) * 128;
    const int n0  = (rem & 7) * 128;

    const float* X = (z == 0) ? Xq : (z == 1) ? Xk : Xv;
    const u16* Wt = (z == 0) ? Wqb : (z == 1) ? Wkb : Wvb;
    const float* bias = (z == 0) ? bq : (z == 1) ? bk : bv;
    u16* out = (z == 0) ? Qh : (z == 1) ? Kh : Vth;

    const int t = threadIdx.x;
    const int w = t >> 6, l = t & 63;
    const int ln = l & 15, hi = l >> 4;
    const int wr = w >> 1, wc = w & 1;

    // A reg-staging geometry: thread t covers row ar, k [ah*16, ah*16+16)
    const int ar = t >> 1, ah = t & 1;
    const float* Xrow = X + (size_t)(m0 + ar) * 1024 + ah * 16;
    // A granule swizzle: k-granule g -> phys gp = g ^ (ar&3)
    const int gpa0 = (2 * ah)     ^ (ar & 3);
    const int gpa1 = (2 * ah + 1) ^ (ar & 3);

    // B gll geometry: gll#i: row = i*64 + t/4, phys granule t&3,
    // source granule gl = (t&3) ^ (row&3)
    const int brow = t >> 2, gp4 = t & 3;
    const int gl4  = gp4 ^ (brow & 3);
    const u16* Wp0 = Wt + (size_t)(n0 + brow) * 1024 + gl4 * 8;
    const u16* Wp1 = Wt + (size_t)(n0 + 64 + brow) * 1024 + gl4 * 8;

    f32x4 acc[4][4];
    #pragma unroll
    for (int i = 0; i < 4; i++)
        #pragma unroll
        for (int j = 0; j < 4; j++)
            acc[i][j] = (f32x4){0.f, 0.f, 0.f, 0.f};

    float4 a0, a1, a2, a3;

#define ISSUE(buf, k0_) {                                                    \
        GLL16(Wp0 + (k0_), &LB[buf][brow][gp4 * 8]);                         \
        GLL16(Wp1 + (k0_), &LB[buf][brow + 64][gp4 * 8]);                    \
        a0 = *(const float4*)(Xrow + (k0_));                                 \
        a1 = *(const float4*)(Xrow + (k0_) + 4);                             \
        a2 = *(const float4*)(Xrow + (k0_) + 8);                             \
        a3 = *(const float4*)(Xrow + (k0_) + 12);                            \
    }

#define CVTWRITE(buf) {                                                      \
        uint4 u0, u1;                                                        \
        u0.x = f2bf(a0.x) | ((unsigned)f2bf(a0.y) << 16);                    \
        u0.y = f2bf(a0.z) | ((unsigned)f2bf(a0.w) << 16);                    \
        u0.z = f2bf(a1.x) | ((unsigned)f2bf(a1.y) << 16);                    \
        u0.w = f2bf(a1.z) | ((unsigned)f2bf(a1.w) << 16);                    \
        u1.x = f2bf(a2.x) | ((unsigned)f2bf(a2.y) << 16);                    \
        u1.y = f2bf(a2.z) | ((unsigned)f2bf(a2.w) << 16);                    \
        u1.z = f2bf(a3.x) | ((unsigned)f2bf(a3.y) << 16);                    \
        u1.w = f2bf(a3.z) | ((unsigned)f2bf(a3.w) << 16);                    \
        *(uint4*)&LA[buf][ar][gpa0 * 8] = u0;                                \
        *(uint4*)&LA[buf][ar][gpa1 * 8] = u1;                                \
    }

    // prologue: tile 0 -> buf 0
    ISSUE(0, 0);
    CVTWRITE(0);
    __syncthreads();

    short8 af[4], bf[4];
    int cur = 0;
    for (int it = 0; it < 32; ++it) {
        const int k0 = it * 32;
        if (it < 31) ISSUE(cur ^ 1, k0 + 32);
        // fragments: granule hi ^ (ln&3) at row (..+ln) holds k-granule hi
        #pragma unroll
        for (int mi = 0; mi < 4; mi++)
            af[mi] = *(const short8*)&LA[cur][wr*64 + mi*16 + ln][(hi ^ (ln & 3)) * 8];
        #pragma unroll
        for (int nj = 0; nj < 4; nj++)
            bf[nj] = *(const short8*)&LB[cur][wc*64 + nj*16 + ln][(hi ^ (ln & 3)) * 8];
        #pragma unroll
        for (int mi = 0; mi < 4; mi++)
            #pragma unroll
            for (int nj = 0; nj < 4; nj++)
                acc[mi][nj] = __builtin_amdgcn_mfma_f32_16x16x32_bf16(
                    af[mi], bf[nj], acc[mi][nj], 0, 0, 0);
        if (it < 31) CVTWRITE(cur ^ 1);
        __syncthreads();
        cur ^= 1;
    }
#undef ISSUE
#undef CVTWRITE

    // epilogue: scatter. lane holds C[row = hi*4+r][col = ln] per frag
    #pragma unroll
    for (int mi = 0; mi < 4; mi++) {
        #pragma unroll
        for (int nj = 0; nj < 4; nj++) {
            const int nb = n0 + wc * 64 + nj * 16 + ln;
            const float bv2 = bias[nb];
            const int h = nb >> 6, d = nb & 63;
            #pragma unroll
            for (int r = 0; r < 4; r++) {
                const int m = m0 + wr * 64 + mi * 16 + hi * 4 + r;
                float v = acc[mi][nj][r] + bv2;
                if (z == 0) v *= QSCALE;
                const int b = m >> 11, s = m & 2047;
                if (z == 2)
                    out[(((size_t)(b * HH + h) * 64 + d) << 11) + s] = f2bf(v);
                else
                    out[((((size_t)(b * HH + h)) << 11) + s) * 64 + d] = f2bf(v);
            }
        }
    }
}

// ---------------------------------------------------------------------------
// Output projection GEMM, 64x128 tile, 1D grid 512 XCD-swizzled, 2-phase
// dbuf; staging coalesced (row-major 64B rows + source XOR swizzle).
// ---------------------------------------------------------------------------
__global__ __launch_bounds__(256)
void gemm_out(const u16* __restrict__ Xb, const u16* __restrict__ Wb,
              const float* __restrict__ bias, float* __restrict__ outp)
{
    __shared__ __align__(16) u16 As[2][64][32];    // 4 KB / buf
    __shared__ __align__(16) u16 Bs[2][128][32];   // 8 KB / buf

    const int bid = blockIdx.x;
    const int swz = (bid & 7) * 64 + (bid >> 3);     // bijective, 512 = 8*64
    const int m0  = (swz >> 3) * 64;
    const int n0  = (swz & 7) * 128;

    const int t = threadIdx.x;
    const int w = t >> 6, l = t & 63;
    const int ln = l & 15, hi = l >> 4;
    const int wr = w >> 1, wc = w & 1;

    const int row0 = t >> 2, gp4 = t & 3;
    const int gl4  = gp4 ^ (row0 & 3);

    f32x4 acc[2][4];
    #pragma unroll
    for (int i = 0; i < 2; i++)
        #pragma unroll
        for (int j = 0; j < 4; j++)
            acc[i][j] = (f32x4){0.f, 0.f, 0.f, 0.f};

#define OSTAGE(buf, k0_) { \
    GLL16(Xb + (size_t)(m0 + row0) * 1024 + (k0_) + gl4 * 8,        \
          &As[buf][row0][gp4 * 8]);                                  \
    GLL16(Wb + (size_t)(n0 + row0) * 1024 + (k0_) + gl4 * 8,        \
          &Bs[buf][row0][gp4 * 8]);                                  \
    GLL16(Wb + (size_t)(n0 + 64 + row0) * 1024 + (k0_) + gl4 * 8,   \
          &Bs[buf][row0 + 64][gp4 * 8]); }

    OSTAGE(0, 0);
    __syncthreads();
    int cur = 0;
    for (int k0 = 0; k0 < 1024; k0 += 32) {
        if (k0 + 32 < 1024) OSTAGE(cur ^ 1, k0 + 32);
        short8 af[2], bfr[4];
        #pragma unroll
        for (int mi = 0; mi < 2; mi++)
            af[mi] = *(const short8*)&As[cur][wr*32 + mi*16 + ln][(hi ^ (ln & 3))*8];
        #pragma unroll
        for (int nj = 0; nj < 4; nj++)
            bfr[nj] = *(const short8*)&Bs[cur][wc*64 + nj*16 + ln][(hi ^ (ln & 3))*8];
        #pragma unroll
        for (int mi = 0; mi < 2; mi++)
            #pragma unroll
            for (int nj = 0; nj < 4; nj++)
                acc[mi][nj] = __builtin_amdgcn_mfma_f32_16x16x32_bf16(
                    af[mi], bfr[nj], acc[mi][nj], 0, 0, 0);
        __syncthreads();
        cur ^= 1;
    }
#undef OSTAGE

    #pragma unroll
    for (int mi = 0; mi < 2; mi++) {
        #pragma unroll
        for (int nj = 0; nj < 4; nj++) {
            const int nb = n0 + wc * 64 + nj * 16 + ln;
            const float bv2 = bias[nb];
            #pragma unroll
            for (int r = 0; r < 4; r++) {
                const int m = m0 + wr * 32 + mi * 16 + hi * 4 + r;
                outp[(size_t)m * 1024 + nb] = acc[mi][nj][r] + bv2;
            }
        }
    }
}

// ---------------------------------------------------------------------------
// Flash attention, bf16 MFMA (unchanged).
// ---------------------------------------------------------------------------
__global__ __launch_bounds__(256)
void attn_mfma(const u16* __restrict__ Qh, const u16* __restrict__ Kh,
               const u16* __restrict__ Vt, u16* __restrict__ Cc)
{
    __shared__ __align__(16) u16 Ks[2][2][4][64][8];  // 16KB
    __shared__ __align__(16) u16 Vs[2][2][4][64][8];  // 16KB
    __shared__ __align__(16) u16 Ps[4][16][64];       // 8KB
    const int bh = blockIdx.x;
    const int y  = 31 - blockIdx.y;        // longest blocks dispatch first
    const int q0 = y * 64;
    const int t = threadIdx.x, w = t >> 6, l = t & 63;
    const int ln = l & 15, hi = l >> 4;
    const size_t base = (size_t)bh * SS * DD;
    const int qg = q0 + w * 16 + ln;

    short8 qf0, qf1;
    {
        const u16* qp = Qh + base + (size_t)qg * 64 + hi * 8;
        qf0 = *(const short8*)qp;
        qf1 = *(const short8*)(qp + 32);
    }
    f32x4 o[4];
    #pragma unroll
    for (int dj = 0; dj < 4; dj++) o[dj] = (f32x4){0.f, 0.f, 0.f, 0.f};
    float mrun = -INFINITY, lrun = 0.f;

#define STAGE(buf, key0_)                                                        \
    {                                                                            \
        _Pragma("unroll")                                                        \
        for (int i_ = 0; i_ < 4; i_++) {                                         \
            const int id_ = w + i_ * 4;                                          \
            if (id_ < 8) {                                                       \
                const int dc_ = id_ >> 2, kg_ = id_ & 3;                         \
                const u16* gp_ = Kh + base + (size_t)((key0_) + l) * 64          \
                                 + dc_ * 32 + kg_ * 8;                           \
                GLL16(gp_, &Ks[buf][dc_][kg_][0][0]);                            \
            } else {                                                             \
                const int kc_ = (id_ >> 2) & 1, kg_ = id_ & 3;                   \
                const u16* gp_ = Vt + base + (size_t)l * SS + (key0_)            \
                                 + kc_ * 32 + kg_ * 8;                           \
                GLL16(gp_, &Vs[buf][kc_][kg_][0][0]);                            \
            }                                                                    \
        }                                                                        \
    }

    STAGE(0, 0);
    __syncthreads();
    int cur = 0;
    const int nkt = y + 1;
    for (int kt = 0; kt < nkt; kt++) {
        const int key0 = kt * 64;
        if (kt + 1 < nkt) STAGE(cur ^ 1, key0 + 64);

        f32x4 st[4];
        #pragma unroll
        for (int kt4 = 0; kt4 < 4; kt4++) {
            short8 ka = *(const short8*)&Ks[cur][0][hi][kt4 * 16 + ln][0];
            short8 kb = *(const short8*)&Ks[cur][1][hi][kt4 * 16 + ln][0];
            f32x4 zz = (f32x4){0.f, 0.f, 0.f, 0.f};
            zz = __builtin_amdgcn_mfma_f32_16x16x32_bf16(ka, qf0, zz, 0, 0, 0);
            zz = __builtin_amdgcn_mfma_f32_16x16x32_bf16(kb, qf1, zz, 0, 0, 0);
            st[kt4] = zz;
        }
        if (kt == y) {
            #pragma unroll
            for (int kt4 = 0; kt4 < 4; kt4++)
                #pragma unroll
                for (int r = 0; r < 4; r++)
                    if (key0 + kt4 * 16 + hi * 4 + r > qg)
                        st[kt4][r] = -INFINITY;
        }

        float tmax = -INFINITY;
        #pragma unroll
        for (int kt4 = 0; kt4 < 4; kt4++)
            #pragma unroll
            for (int r = 0; r < 4; r++)
                tmax = fmaxf(tmax, st[kt4][r]);
        tmax = fmaxf(tmax, __shfl_xor(tmax, 16));
        tmax = fmaxf(tmax, __shfl_xor(tmax, 32));
        if (__ballot(tmax > mrun + 8.f)) {      // deferred-max rescale (T13)
            const float mnew = fmaxf(mrun, tmax);
            const float alpha = exp2_fast(mrun - mnew);
            lrun *= alpha;
            mrun = mnew;
            #pragma unroll
            for (int r = 0; r < 4; r++) {
                const float ar = __shfl(alpha, hi * 4 + r);
                #pragma unroll
                for (int dj = 0; dj < 4; dj++) o[dj][r] *= ar;
            }
        }
        float p[4][4];
        float lsum = 0.f;
        #pragma unroll
        for (int kt4 = 0; kt4 < 4; kt4++)
            #pragma unroll
            for (int r = 0; r < 4; r++) {
                p[kt4][r] = exp2_fast(st[kt4][r] - mrun);
                lsum += p[kt4][r];
            }
        lsum += __shfl_xor(lsum, 16);
        lsum += __shfl_xor(lsum, 32);
        lrun += lsum;

        char* prow = ((char*)Ps) + (w * 16 + ln) * 128 + (hi & 1) * 8;
        #pragma unroll
        for (int kt4 = 0; kt4 < 4; kt4++) {
            unsigned dw0, dw1;
            asm("v_cvt_pk_bf16_f32 %0, %1, %2" : "=v"(dw0)
                : "v"(p[kt4][0]), "v"(p[kt4][1]));
            asm("v_cvt_pk_bf16_f32 %0, %1, %2" : "=v"(dw1)
                : "v"(p[kt4][2]), "v"(p[kt4][3]));
            const int g = (2 * kt4 + (hi >> 1)) ^ (ln & 7);
            *(uint2*)(prow + g * 16) = make_uint2(dw0, dw1);
        }

        #pragma unroll
        for (int kc = 0; kc < 2; kc++) {
            const int gr = (kc * 4 + hi) ^ (ln & 7);
            short8 pa = *(const short8*)(((char*)Ps) + (w * 16 + ln) * 128 + gr * 16);
            #pragma unroll
            for (int dj = 0; dj < 4; dj++) {
                short8 vb = *(const short8*)&Vs[cur][kc][hi][dj * 16 + ln][0];
                o[dj] = __builtin_amdgcn_mfma_f32_16x16x32_bf16(pa, vb, o[dj], 0, 0, 0);
            }
        }
        __syncthreads();
        cur ^= 1;
    }
#undef STAGE

    const float inv = 1.f / lrun;
    #pragma unroll
    for (int r = 0; r < 4; r++) {
        const float ir = __shfl(inv, hi * 4 + r);
        const int s = q0 + w * 16 + hi * 4 + r;
        const size_t ob = ((size_t)(bh >> 4) * SS + s) * EE + (bh & 15) * 64;
        #pragma unroll
        for (int dj = 0; dj < 4; dj++)
            Cc[ob + dj * 16 + ln] = f2bf(o[dj][r] * ir);
    }
}

extern "C" void kernel_launch(void* const* d_in, const int* in_sizes, int n_in,
                              void* d_out, int out_size, void* d_ws, size_t ws_size,
                              hipStream_t stream)
{
    (void)in_sizes; (void)n_in; (void)out_size; (void)ws_size;
    const float* query = (const float*)d_in[0];
    const float* key   = (const float*)d_in[1];
    const float* value = (const float*)d_in[2];
    // d_in[3] = mask: exactly causal tril, implemented analytically
    const float* Wq = (const float*)d_in[4];
    const float* bq = (const float*)d_in[5];
    const float* Wk = (const float*)d_in[6];
    const float* bk = (const float*)d_in[7];
    const float* Wv = (const float*)d_in[8];
    const float* bv = (const float*)d_in[9];
    const float* Wo = (const float*)d_in[10];
    const float* bo = (const float*)d_in[11];
    float* out = (float*)d_out;

    char* ws = (char*)d_ws;
    u16* Wqb = (u16*)(ws + 25165824);             // 2 MiB
    u16* Wkb = (u16*)(ws + 27262976);             // 2 MiB
    u16* Wvb = (u16*)(ws + 29360128);             // 2 MiB
    u16* Wob = (u16*)(ws + 31457280);             // 2 MiB
    u16* Qh  = (u16*)(ws + 33554432);             // 8 MiB [b,h][s][d]
    u16* Kh  = (u16*)(ws + 41943040);             // 8 MiB [b,h][s][d]
    u16* Vth = (u16*)(ws + 50331648);             // 8 MiB [b,h][d][s]
    u16* Cc  = (u16*)(ws + 58720256);             // 8 MiB [b][s][e]

    cvt_bf16<<<dim3(512, 4), 256, 0, stream>>>(
        Wq, Wk, Wv, Wo, Wqb, Wkb, Wvb, Wob);

    gemm_qkv<<<768, 256, 0, stream>>>(
        query, key, value, Wqb, Wkb, Wvb, bq, bk, bv, Qh, Kh, Vth);
    attn_mfma<<<dim3(32, 32), 256, 0, stream>>>(Qh, Kh, Vth, Cc);
    gemm_out<<<512, 256, 0, stream>>>(Cc, Wob, bo, out);
}